// Round 5
// baseline (127.006 us; speedup 1.0000x reference)
//
#include <hip/hip_runtime.h>
#include <stdint.h>

#define NB 4096      // B
#define NT 819200    // T
#define NI 100000    // num items
#define MUF 3.5f
#define FP8_SCALE 256.0f
#define FP8_INV   (1.0f/256.0f)

#if defined(__has_builtin)
#if __has_builtin(__builtin_amdgcn_cvt_pk_f32_fp8) && __has_builtin(__builtin_amdgcn_cvt_pk_fp8_f32)
#define HAVE_FP8_CVT 1
#endif
#endif
#ifndef HAVE_FP8_CVT
#define HAVE_FP8_CVT 0
#endif

typedef float floatx2 __attribute__((ext_vector_type(2)));

#if HAVE_FP8_CVT
// ws: XYp = uint4[NI*16]; per item 256B: slot l covers dims 8l..8l+7:
//   v.x = fp8x4 X[d0..d3], v.y = fp8x4 X[d4..d7], v.z = Y[d0..d3], v.w = Y[d4..d7]
#define WS_NEEDED ((size_t)NI * 16 * 16)   // 25,600,000 B

__device__ __forceinline__ uint32_t pack4_fp8(float a, float b, float c, float d) {
    uint32_t u = 0;
    u = __builtin_amdgcn_cvt_pk_fp8_f32(a, b, u, false);
    u = __builtin_amdgcn_cvt_pk_fp8_f32(c, d, u, true);
    return u;
}

// ============ K0: pack X,Y (fp32) -> fp8, scaled by 256 ============
__global__ __launch_bounds__(256) void k_pack(const float* __restrict__ X,
                                              const float* __restrict__ Y,
                                              uint4* __restrict__ XYp) {
    int idx = blockIdx.x * 256 + threadIdx.x;      // over NI*16 slots
    if (idx >= NI * 16) return;
    int i = idx >> 4, l = idx & 15;
    const float4* X4 = (const float4*)X;
    const float4* Y4 = (const float4*)Y;
    float4 xa = X4[(size_t)i * 32 + 2 * l];
    float4 xb = X4[(size_t)i * 32 + 2 * l + 1];
    float4 ya = Y4[(size_t)i * 32 + 2 * l];
    float4 yb = Y4[(size_t)i * 32 + 2 * l + 1];
    uint4 v;
    v.x = pack4_fp8(xa.x * FP8_SCALE, xa.y * FP8_SCALE, xa.z * FP8_SCALE, xa.w * FP8_SCALE);
    v.y = pack4_fp8(xb.x * FP8_SCALE, xb.y * FP8_SCALE, xb.z * FP8_SCALE, xb.w * FP8_SCALE);
    v.z = pack4_fp8(ya.x * FP8_SCALE, ya.y * FP8_SCALE, ya.z * FP8_SCALE, ya.w * FP8_SCALE);
    v.w = pack4_fp8(yb.x * FP8_SCALE, yb.y * FP8_SCALE, yb.z * FP8_SCALE, yb.w * FP8_SCALE);
    XYp[idx] = v;
}

// ============ K1: main — 16 entry-groups/block, 16 lanes/row ============
__global__ __launch_bounds__(256) void asvd_main(
    const float* __restrict__ bu, const float* __restrict__ bi,
    const float* __restrict__ Q,
    const uint4* __restrict__ XYp,
    const int* __restrict__ user, const int* __restrict__ item,
    const int* __restrict__ imp_items, const int* __restrict__ imp_ratings,
    const int* __restrict__ seg, float* __restrict__ out)
{
    const int b   = blockIdx.x;
    const int tid = threadIdx.x;

    auto lower = [&](int key) {
        int lo = 0, hi = NT;
        while (lo < hi) {
            int mid = (lo + hi) >> 1;
            if (seg[mid] < key) lo = mid + 1; else hi = mid;
        }
        return lo;
    };
    const int start = lower(b);
    const int end   = lower(b + 1);
    const int count = end - start;

    const int   u    = user[b];
    const int   it   = item[b];
    const float bu_u = bu[u];
    const float bui  = MUF + bu_u + bi[it];

    const int g = tid >> 4;   // entry group 0..15
    const int l = tid & 15;   // 16B slot within the 256B packed row

    float acc[8] = {0.f,0.f,0.f,0.f,0.f,0.f,0.f,0.f};

    int t = start + g;
    for (; t + 16 < end; t += 32) {
        const int j0 = imp_items[t];
        const int j1 = imp_items[t + 16];
        const int r0 = imp_ratings[t];
        const int r1 = imp_ratings[t + 16];
        const float w0 = (float)r0 - MUF - bu_u - bi[j0];
        const float w1 = (float)r1 - MUF - bu_u - bi[j1];
        const uint4 v0 = XYp[(size_t)j0 * 16 + l];
        const uint4 v1 = XYp[(size_t)j1 * 16 + l];

        {
            floatx2 x01 = __builtin_amdgcn_cvt_pk_f32_fp8(v0.x, false);
            floatx2 x23 = __builtin_amdgcn_cvt_pk_f32_fp8(v0.x, true);
            floatx2 x45 = __builtin_amdgcn_cvt_pk_f32_fp8(v0.y, false);
            floatx2 x67 = __builtin_amdgcn_cvt_pk_f32_fp8(v0.y, true);
            floatx2 y01 = __builtin_amdgcn_cvt_pk_f32_fp8(v0.z, false);
            floatx2 y23 = __builtin_amdgcn_cvt_pk_f32_fp8(v0.z, true);
            floatx2 y45 = __builtin_amdgcn_cvt_pk_f32_fp8(v0.w, false);
            floatx2 y67 = __builtin_amdgcn_cvt_pk_f32_fp8(v0.w, true);
            acc[0] += w0 * x01.x + y01.x;  acc[1] += w0 * x01.y + y01.y;
            acc[2] += w0 * x23.x + y23.x;  acc[3] += w0 * x23.y + y23.y;
            acc[4] += w0 * x45.x + y45.x;  acc[5] += w0 * x45.y + y45.y;
            acc[6] += w0 * x67.x + y67.x;  acc[7] += w0 * x67.y + y67.y;
        }
        {
            floatx2 x01 = __builtin_amdgcn_cvt_pk_f32_fp8(v1.x, false);
            floatx2 x23 = __builtin_amdgcn_cvt_pk_f32_fp8(v1.x, true);
            floatx2 x45 = __builtin_amdgcn_cvt_pk_f32_fp8(v1.y, false);
            floatx2 x67 = __builtin_amdgcn_cvt_pk_f32_fp8(v1.y, true);
            floatx2 y01 = __builtin_amdgcn_cvt_pk_f32_fp8(v1.z, false);
            floatx2 y23 = __builtin_amdgcn_cvt_pk_f32_fp8(v1.z, true);
            floatx2 y45 = __builtin_amdgcn_cvt_pk_f32_fp8(v1.w, false);
            floatx2 y67 = __builtin_amdgcn_cvt_pk_f32_fp8(v1.w, true);
            acc[0] += w1 * x01.x + y01.x;  acc[1] += w1 * x01.y + y01.y;
            acc[2] += w1 * x23.x + y23.x;  acc[3] += w1 * x23.y + y23.y;
            acc[4] += w1 * x45.x + y45.x;  acc[5] += w1 * x45.y + y45.y;
            acc[6] += w1 * x67.x + y67.x;  acc[7] += w1 * x67.y + y67.y;
        }
    }
    for (; t < end; t += 16) {
        const int j = imp_items[t];
        const float w = (float)imp_ratings[t] - MUF - bu_u - bi[j];
        const uint4 v = XYp[(size_t)j * 16 + l];
        floatx2 x01 = __builtin_amdgcn_cvt_pk_f32_fp8(v.x, false);
        floatx2 x23 = __builtin_amdgcn_cvt_pk_f32_fp8(v.x, true);
        floatx2 x45 = __builtin_amdgcn_cvt_pk_f32_fp8(v.y, false);
        floatx2 x67 = __builtin_amdgcn_cvt_pk_f32_fp8(v.y, true);
        floatx2 y01 = __builtin_amdgcn_cvt_pk_f32_fp8(v.z, false);
        floatx2 y23 = __builtin_amdgcn_cvt_pk_f32_fp8(v.z, true);
        floatx2 y45 = __builtin_amdgcn_cvt_pk_f32_fp8(v.w, false);
        floatx2 y67 = __builtin_amdgcn_cvt_pk_f32_fp8(v.w, true);
        acc[0] += w * x01.x + y01.x;  acc[1] += w * x01.y + y01.y;
        acc[2] += w * x23.x + y23.x;  acc[3] += w * x23.y + y23.y;
        acc[4] += w * x45.x + y45.x;  acc[5] += w * x45.y + y45.y;
        acc[6] += w * x67.x + y67.x;  acc[7] += w * x67.y + y67.y;
    }

    const float4* Q4 = (const float4*)Q;
    const float4 qa = Q4[(size_t)it * 32 + 2 * l];
    const float4 qb = Q4[(size_t)it * 32 + 2 * l + 1];
    float partial = acc[0] * qa.x + acc[1] * qa.y + acc[2] * qa.z + acc[3] * qa.w
                  + acc[4] * qb.x + acc[5] * qb.y + acc[6] * qb.z + acc[7] * qb.w;

    // reduce within 16-lane group (xor butterfly stays inside group)
    #pragma unroll
    for (int m = 8; m > 0; m >>= 1)
        partial += __shfl_xor(partial, m, 64);

    __shared__ float red[16];
    if (l == 0) red[g] = partial;
    __syncthreads();
    if (tid == 0) {
        float tot = 0.f;
        #pragma unroll
        for (int i = 0; i < 16; ++i) tot += red[i];
        const float norm = (count > 0) ? rsqrtf((float)count) : 1.0f;
        out[b] = bui + norm * tot * FP8_INV;
    }
}
#else
#define WS_NEEDED ((size_t)1 << 60)   // force fallback if no fp8 cvt builtins
#endif

// ============ fallback (round-1 kernel) ============
__global__ __launch_bounds__(256) void asvd_fallback(
    const float* __restrict__ bu, const float* __restrict__ bi,
    const float* __restrict__ Q,  const float* __restrict__ X,
    const float* __restrict__ Y,
    const int* __restrict__ user, const int* __restrict__ item,
    const int* __restrict__ imp_items, const int* __restrict__ imp_ratings,
    const int* __restrict__ seg, float* __restrict__ out)
{
    const int b   = blockIdx.x;
    const int tid = threadIdx.x;
    auto lower = [&](int key) {
        int lo = 0, hi = NT;
        while (lo < hi) {
            int mid = (lo + hi) >> 1;
            if (seg[mid] < key) lo = mid + 1; else hi = mid;
        }
        return lo;
    };
    const int start = lower(b);
    const int end   = lower(b + 1);
    const int count = end - start;
    const int   u    = user[b];
    const int   it   = item[b];
    const float bu_u = bu[u];
    const float bui  = MUF + bu_u + bi[it];
    const int g = tid >> 5;
    const int l = tid & 31;
    const float4* X4 = (const float4*)X;
    const float4* Y4 = (const float4*)Y;
    const float4* Q4 = (const float4*)Q;
    float4 acc = make_float4(0.f, 0.f, 0.f, 0.f);
    for (int t = start + g; t < end; t += 8) {
        const int   j = imp_items[t];
        const float w = (float)imp_ratings[t] - MUF - bu_u - bi[j];
        const float4 x = X4[(size_t)j * 32 + l];
        const float4 y = Y4[(size_t)j * 32 + l];
        acc.x += w * x.x + y.x;  acc.y += w * x.y + y.y;
        acc.z += w * x.z + y.z;  acc.w += w * x.w + y.w;
    }
    const float4 q = Q4[(size_t)it * 32 + l];
    float partial = acc.x * q.x + acc.y * q.y + acc.z * q.z + acc.w * q.w;
    #pragma unroll
    for (int off = 32; off > 0; off >>= 1)
        partial += __shfl_down(partial, off, 64);
    __shared__ float red[4];
    if ((tid & 63) == 0) red[tid >> 6] = partial;
    __syncthreads();
    if (tid == 0) {
        const float total = red[0] + red[1] + red[2] + red[3];
        const float norm  = (count > 0) ? rsqrtf((float)count) : 1.0f;
        out[b] = bui + norm * total;
    }
}

extern "C" void kernel_launch(void* const* d_in, const int* in_sizes, int n_in,
                              void* d_out, int out_size, void* d_ws, size_t ws_size,
                              hipStream_t stream) {
    const float* bu = (const float*)d_in[0];
    const float* bi = (const float*)d_in[1];
    const float* Q  = (const float*)d_in[2];
    const float* X  = (const float*)d_in[3];
    const float* Y  = (const float*)d_in[4];
    const int* user        = (const int*)d_in[5];
    const int* item        = (const int*)d_in[6];
    const int* imp_items   = (const int*)d_in[7];
    const int* imp_ratings = (const int*)d_in[8];
    const int* seg         = (const int*)d_in[9];
    float* out = (float*)d_out;

#if HAVE_FP8_CVT
    if (ws_size >= WS_NEEDED) {
        uint4* XYp = (uint4*)d_ws;
        k_pack<<<(NI * 16 + 255) / 256, 256, 0, stream>>>(X, Y, XYp);
        asvd_main<<<NB, 256, 0, stream>>>(bu, bi, Q, XYp, user, item,
                                          imp_items, imp_ratings, seg, out);
        return;
    }
#endif
    asvd_fallback<<<NB, 256, 0, stream>>>(bu, bi, Q, X, Y, user, item,
                                          imp_items, imp_ratings, seg, out);
}

// Round 6
// 82.743 us; speedup vs baseline: 1.5349x; 1.5349x over previous
//
#include <hip/hip_runtime.h>
#include <stdint.h>

#define NB 4096      // B
#define NT 819200    // T
#define NI 100000    // num items
#define MUF 3.5f

// ---- ws layout (bytes): int8 rows + scales + per-entry streams ----
#define XYP_OFF 0u                  // uint4[NI*16] : 256B/item (128 i8 X | 128 i8 Y)
#define SC_OFF  25600000u           // float2[NI]   : {sx, sy}
#define WSX_OFF 26400000u           // float[NT]    : w(t) * sx[j(t)]
#define SYT_OFF 29676800u           // float[NT]    : sy[j(t)]
#define WS_NEEDED 32953600u

// ============ K0: per-item max-abs scale + int8 quantize ============
__global__ __launch_bounds__(256) void k_scale(const float* __restrict__ X,
                                               const float* __restrict__ Y,
                                               char* __restrict__ ws) {
    const int tid = threadIdx.x;
    const int i = blockIdx.x * 16 + (tid >> 4);   // item
    const int l = tid & 15;                       // slot: dims 8l..8l+7
    if (i >= NI) return;
    uint4* XYp = (uint4*)(ws + XYP_OFF);
    float2* SC = (float2*)(ws + SC_OFF);
    const float4* X4 = (const float4*)X;
    const float4* Y4 = (const float4*)Y;

    float4 xa = X4[(size_t)i * 32 + 2 * l];
    float4 xb = X4[(size_t)i * 32 + 2 * l + 1];
    float4 ya = Y4[(size_t)i * 32 + 2 * l];
    float4 yb = Y4[(size_t)i * 32 + 2 * l + 1];

    float mx = fmaxf(fmaxf(fmaxf(fabsf(xa.x), fabsf(xa.y)), fmaxf(fabsf(xa.z), fabsf(xa.w))),
                     fmaxf(fmaxf(fabsf(xb.x), fabsf(xb.y)), fmaxf(fabsf(xb.z), fabsf(xb.w))));
    float my = fmaxf(fmaxf(fmaxf(fabsf(ya.x), fabsf(ya.y)), fmaxf(fabsf(ya.z), fabsf(ya.w))),
                     fmaxf(fmaxf(fabsf(yb.x), fabsf(yb.y)), fmaxf(fabsf(yb.z), fabsf(yb.w))));
    #pragma unroll
    for (int m = 8; m > 0; m >>= 1) {
        mx = fmaxf(mx, __shfl_xor(mx, m, 64));
        my = fmaxf(my, __shfl_xor(my, m, 64));
    }
    const float invx = (mx > 0.f) ? 127.0f / mx : 0.f;
    const float invy = (my > 0.f) ? 127.0f / my : 0.f;

    auto pb = [](float a, float b, float c, float d, float inv) -> uint32_t {
        int ia = __float2int_rn(a * inv), ib = __float2int_rn(b * inv);
        int ic = __float2int_rn(c * inv), id = __float2int_rn(d * inv);
        return (uint32_t)(ia & 255) | ((uint32_t)(ib & 255) << 8) |
               ((uint32_t)(ic & 255) << 16) | ((uint32_t)(id & 255) << 24);
    };
    uint4 v;
    v.x = pb(xa.x, xa.y, xa.z, xa.w, invx);
    v.y = pb(xb.x, xb.y, xb.z, xb.w, invx);
    v.z = pb(ya.x, ya.y, ya.z, ya.w, invy);
    v.w = pb(yb.x, yb.y, yb.z, yb.w, invy);
    XYp[(size_t)i * 16 + l] = v;
    if (l == 0) SC[i] = make_float2(mx * (1.0f / 127.0f), my * (1.0f / 127.0f));
}

// ============ K1: per-entry streams wsx, syt ============
__global__ __launch_bounds__(256) void k_w(const float* __restrict__ bu,
                                           const float* __restrict__ bi,
                                           const int* __restrict__ user,
                                           const int* __restrict__ imp_items,
                                           const int* __restrict__ imp_ratings,
                                           const int* __restrict__ seg,
                                           char* __restrict__ ws) {
    const int t = blockIdx.x * 256 + threadIdx.x;
    const float2* SC = (const float2*)(ws + SC_OFF);
    float* wsx = (float*)(ws + WSX_OFF);
    float* syt = (float*)(ws + SYT_OFF);
    const int j = imp_items[t];
    const int b = seg[t];
    const float w = (float)imp_ratings[t] - MUF - bu[user[b]] - bi[j];
    const float2 s = SC[j];
    wsx[t] = w * s.x;
    syt[t] = s.y;
}

// ============ K2: main — 16 groups/block, 16 lanes/row, 4 chains ============
__global__ __launch_bounds__(256) void asvd_main(
    const float* __restrict__ bu, const float* __restrict__ bi,
    const float* __restrict__ Q,
    const int* __restrict__ user, const int* __restrict__ item,
    const int* __restrict__ imp_items,
    const int* __restrict__ seg,
    const char* __restrict__ ws, float* __restrict__ out)
{
    const int b   = blockIdx.x;
    const int tid = threadIdx.x;

    auto lower = [&](int key) {
        int lo = 0, hi = NT;
        while (lo < hi) {
            int mid = (lo + hi) >> 1;
            if (seg[mid] < key) lo = mid + 1; else hi = mid;
        }
        return lo;
    };
    const int start = lower(b);
    const int end   = lower(b + 1);
    const int count = end - start;

    const float bui = MUF + bu[user[b]] + bi[item[b]];
    const int   it  = item[b];

    const int g = tid >> 4;   // entry group 0..15
    const int l = tid & 15;   // 16B slot (dims 8l..8l+7)

    const uint4* __restrict__ XYp = (const uint4*)(ws + XYP_OFF);
    const float* __restrict__ wsx = (const float*)(ws + WSX_OFF);
    const float* __restrict__ syt = (const float*)(ws + SYT_OFF);

    float acc[8] = {0.f,0.f,0.f,0.f,0.f,0.f,0.f,0.f};

#define DEC_ACC(v, wx, sy) do { \
    acc[0] += (wx) * (float)((int)((v).x << 24) >> 24) + (sy) * (float)((int)((v).z << 24) >> 24); \
    acc[1] += (wx) * (float)((int)((v).x << 16) >> 24) + (sy) * (float)((int)((v).z << 16) >> 24); \
    acc[2] += (wx) * (float)((int)((v).x <<  8) >> 24) + (sy) * (float)((int)((v).z <<  8) >> 24); \
    acc[3] += (wx) * (float)((int)(v).x        >> 24) + (sy) * (float)((int)(v).z        >> 24); \
    acc[4] += (wx) * (float)((int)((v).y << 24) >> 24) + (sy) * (float)((int)((v).w << 24) >> 24); \
    acc[5] += (wx) * (float)((int)((v).y << 16) >> 24) + (sy) * (float)((int)((v).w << 16) >> 24); \
    acc[6] += (wx) * (float)((int)((v).y <<  8) >> 24) + (sy) * (float)((int)((v).w <<  8) >> 24); \
    acc[7] += (wx) * (float)((int)(v).y        >> 24) + (sy) * (float)((int)(v).w        >> 24); \
} while (0)

    int t = start + g;
    for (; t + 48 < end; t += 64) {
        const int j0 = imp_items[t];
        const int j1 = imp_items[t + 16];
        const int j2 = imp_items[t + 32];
        const int j3 = imp_items[t + 48];
        const float wx0 = wsx[t],      sy0 = syt[t];
        const float wx1 = wsx[t + 16], sy1 = syt[t + 16];
        const float wx2 = wsx[t + 32], sy2 = syt[t + 32];
        const float wx3 = wsx[t + 48], sy3 = syt[t + 48];
        const uint4 v0 = XYp[(size_t)j0 * 16 + l];
        const uint4 v1 = XYp[(size_t)j1 * 16 + l];
        const uint4 v2 = XYp[(size_t)j2 * 16 + l];
        const uint4 v3 = XYp[(size_t)j3 * 16 + l];
        DEC_ACC(v0, wx0, sy0);
        DEC_ACC(v1, wx1, sy1);
        DEC_ACC(v2, wx2, sy2);
        DEC_ACC(v3, wx3, sy3);
    }
    for (; t < end; t += 16) {
        const int j = imp_items[t];
        const float wx = wsx[t], sy = syt[t];
        const uint4 v = XYp[(size_t)j * 16 + l];
        DEC_ACC(v, wx, sy);
    }
#undef DEC_ACC

    const float4* Q4 = (const float4*)Q;
    const float4 qa = Q4[(size_t)it * 32 + 2 * l];
    const float4 qb = Q4[(size_t)it * 32 + 2 * l + 1];
    float partial = acc[0] * qa.x + acc[1] * qa.y + acc[2] * qa.z + acc[3] * qa.w
                  + acc[4] * qb.x + acc[5] * qb.y + acc[6] * qb.z + acc[7] * qb.w;

    #pragma unroll
    for (int m = 8; m > 0; m >>= 1)
        partial += __shfl_xor(partial, m, 64);

    __shared__ float red[16];
    if (l == 0) red[g] = partial;
    __syncthreads();
    if (tid == 0) {
        float tot = 0.f;
        #pragma unroll
        for (int i = 0; i < 16; ++i) tot += red[i];
        const float norm = (count > 0) ? rsqrtf((float)count) : 1.0f;
        out[b] = bui + norm * tot;
    }
}

// ============ fallback (round-1 kernel) ============
__global__ __launch_bounds__(256) void asvd_fallback(
    const float* __restrict__ bu, const float* __restrict__ bi,
    const float* __restrict__ Q,  const float* __restrict__ X,
    const float* __restrict__ Y,
    const int* __restrict__ user, const int* __restrict__ item,
    const int* __restrict__ imp_items, const int* __restrict__ imp_ratings,
    const int* __restrict__ seg, float* __restrict__ out)
{
    const int b   = blockIdx.x;
    const int tid = threadIdx.x;
    auto lower = [&](int key) {
        int lo = 0, hi = NT;
        while (lo < hi) {
            int mid = (lo + hi) >> 1;
            if (seg[mid] < key) lo = mid + 1; else hi = mid;
        }
        return lo;
    };
    const int start = lower(b);
    const int end   = lower(b + 1);
    const int count = end - start;
    const int   u    = user[b];
    const int   it   = item[b];
    const float bu_u = bu[u];
    const float bui  = MUF + bu_u + bi[it];
    const int g = tid >> 5;
    const int l = tid & 31;
    const float4* X4 = (const float4*)X;
    const float4* Y4 = (const float4*)Y;
    const float4* Q4 = (const float4*)Q;
    float4 acc = make_float4(0.f, 0.f, 0.f, 0.f);
    for (int t = start + g; t < end; t += 8) {
        const int   j = imp_items[t];
        const float w = (float)imp_ratings[t] - MUF - bu_u - bi[j];
        const float4 x = X4[(size_t)j * 32 + l];
        const float4 y = Y4[(size_t)j * 32 + l];
        acc.x += w * x.x + y.x;  acc.y += w * x.y + y.y;
        acc.z += w * x.z + y.z;  acc.w += w * x.w + y.w;
    }
    const float4 q = Q4[(size_t)it * 32 + l];
    float partial = acc.x * q.x + acc.y * q.y + acc.z * q.z + acc.w * q.w;
    #pragma unroll
    for (int off = 32; off > 0; off >>= 1)
        partial += __shfl_down(partial, off, 64);
    __shared__ float red[4];
    if ((tid & 63) == 0) red[tid >> 6] = partial;
    __syncthreads();
    if (tid == 0) {
        const float total = red[0] + red[1] + red[2] + red[3];
        const float norm  = (count > 0) ? rsqrtf((float)count) : 1.0f;
        out[b] = bui + norm * total;
    }
}

extern "C" void kernel_launch(void* const* d_in, const int* in_sizes, int n_in,
                              void* d_out, int out_size, void* d_ws, size_t ws_size,
                              hipStream_t stream) {
    const float* bu = (const float*)d_in[0];
    const float* bi = (const float*)d_in[1];
    const float* Q  = (const float*)d_in[2];
    const float* X  = (const float*)d_in[3];
    const float* Y  = (const float*)d_in[4];
    const int* user        = (const int*)d_in[5];
    const int* item        = (const int*)d_in[6];
    const int* imp_items   = (const int*)d_in[7];
    const int* imp_ratings = (const int*)d_in[8];
    const int* seg         = (const int*)d_in[9];
    float* out = (float*)d_out;

    if (ws_size < (size_t)WS_NEEDED) {
        asvd_fallback<<<NB, 256, 0, stream>>>(bu, bi, Q, X, Y, user, item,
                                              imp_items, imp_ratings, seg, out);
        return;
    }
    char* ws = (char*)d_ws;

    k_scale<<<(NI + 15) / 16, 256, 0, stream>>>(X, Y, ws);
    k_w<<<NT / 256, 256, 0, stream>>>(bu, bi, user, imp_items, imp_ratings, seg, ws);
    asvd_main<<<NB, 256, 0, stream>>>(bu, bi, Q, user, item, imp_items, seg, ws, out);
}